// Round 4
// baseline (43476.416 us; speedup 1.0000x reference)
//
#include <hip/hip_runtime.h>

typedef float f32x2 __attribute__((ext_vector_type(2)));
typedef float f32x4 __attribute__((ext_vector_type(4)));

#define BB 64
#define TT 1024
#define DIN 128
#define NB 256
#define KW 5
#define HID 512
#define LL 510
#define LT 32
#define KTOT 768          // NB + HID
#define ROWS 2048         // 4*HID
#define EPS 1e-5f

// ---------------- prep: wT[k][r] = W[r][k] (W = [W_ih | W_hh]), biasv = b_ih+b_hh ----
__global__ __launch_bounds__(256) void prep_kernel(
    const float* __restrict__ wih, const float* __restrict__ whh,
    const float* __restrict__ bih, const float* __restrict__ bhh,
    float* __restrict__ wT, float* __restrict__ biasv)
{
  const int blk = blockIdx.x, tid = threadIdx.x;
  if (blk < (KTOT*ROWS)/256) {
    const int e = blk*256 + tid;
    const int k = e >> 11, r = e & (ROWS-1);
    wT[e] = (k < NB) ? wih[(size_t)r*NB + k] : whh[(size_t)r*HID + (k-NB)];
  } else {
    const int r = (blk - (KTOT*ROWS)/256)*256 + tid;
    if (r < ROWS) biasv[r] = bih[r] + bhh[r];
  }
}

// ---------------- Conv1d + ReLU + BatchNorm (eval) -> seq[B][L][NB] ----------------
__global__ __launch_bounds__(256) void conv_kernel(
    const float* __restrict__ x, const float* __restrict__ cw,
    const float* __restrict__ cb, const float* __restrict__ gma,
    const float* __restrict__ bta, const float* __restrict__ bmean,
    const float* __restrict__ bvar, float* __restrict__ seq)
{
  __shared__ float xt[2*LT+3][DIN];
  const int b = blockIdx.y, lc = blockIdx.x, tid = threadIdx.x;
  const int l0 = lc*LT, t0 = l0*2;

  const float4* x4 = (const float4*)(x + ((size_t)b*TT + t0)*DIN);
  for (int i = tid; i < (2*LT+3)*(DIN/4); i += 256) {
    const int r = i >> 5, c = i & 31;
    float4 v = make_float4(0.f, 0.f, 0.f, 0.f);
    if (t0 + r < TT) v = x4[(size_t)r*(DIN/4) + c];
    ((float4*)xt[r])[c] = v;
  }
  __syncthreads();

  const int f = tid;
  float acc[LT];
#pragma unroll
  for (int l = 0; l < LT; ++l) acc[l] = 0.f;

  const float* wr = cw + (size_t)f*(DIN*KW);
  for (int d = 0; d < DIN; ++d) {
    float xr[2*LT+3];
#pragma unroll
    for (int r = 0; r < 2*LT+3; ++r) xr[r] = xt[r][d];
#pragma unroll
    for (int k = 0; k < KW; ++k) {
      const float w = wr[d*KW + k];
#pragma unroll
      for (int l = 0; l < LT; ++l) acc[l] += w * xr[2*l + k];
    }
  }

  const float bias  = cb[f];
  const float scale = gma[f] * rsqrtf(bvar[f] + EPS);
  const float shift = bta[f] - bmean[f]*scale;
#pragma unroll
  for (int l = 0; l < LT; ++l) {
    const int ll = l0 + l;
    if (ll < LL) {
      float y = acc[l] + bias;
      y = fmaxf(y, 0.f);
      seq[((size_t)b*LL + ll)*NB + f] = y*scale + shift;
    }
  }
}

// ---------------- SkipLSTM recurrence: ONE BATCH PER BLOCK, zero cross-block sync ---
// 64 blocks x 1024 threads. z_lds[768] = [x_t | h_t]. Thread computes gate rows
// 2*tid, 2*tid+1: acc2 += wT[k][2tid..2tid+1] * z[k]  (coalesced 8B/lane weight
// stream, shared across the 8 sibling blocks of each XCD via L2). All state
// (c in regs, h/x/u in LDS) is block-local; 3 __syncthreads per step.
__global__ __launch_bounds__(1024) void rec_kernel(
    const float* __restrict__ seq, const float* __restrict__ wT,
    const float* __restrict__ biasv, const float* __restrict__ wu,
    const float* __restrict__ bu, float* __restrict__ out)
{
  __shared__ float zs[KTOT];        // [x(256) | h(512)]
  __shared__ float gact[ROWS];      // activated gates, 8 KB
  __shared__ float part[8];
  __shared__ float u_s, ut_s;

  const int tid = threadIdx.x;
  const int b   = blockIdx.x;
  const float* seqb = seq + (size_t)b*LL*NB;

  const f32x2 bias2 = ((const f32x2*)biasv)[tid];
  const float wuj   = (tid < HID) ? wu[tid] : 0.f;
  const float buv   = bu[0];
  const int   g     = tid >> 8;           // gate of rows 2tid,2tid+1 (0=i,1=f,2=g,3=o)

  float c_reg = 0.f;

  // init: x_0 into zs[0:256], h_0 = 0
  for (int i = tid; i < NB; i += 1024) zs[i] = seqb[i];
  for (int i = NB + tid; i < KTOT; i += 1024) zs[i] = 0.f;
  if (tid == 0) { u_s = 1.f; ut_s = 1.f; }
  __syncthreads();

  for (int t = 0; t < LL; ++t) {
    // prefetch x_{t+1} into registers (consumed after the k-loop)
    f32x4 xr;
    if (tid < 64 && t+1 < LL)
      xr = *(const f32x4*)(seqb + (size_t)(t+1)*NB + 4*tid);

    // ---- P1: GEMV. acc2 = bias + sum_k wT[k][2tid..2tid+1] * z[k] ----
    f32x2 acc = bias2;
    {
      const f32x2* wp = (const f32x2*)wT + tid;
#pragma unroll 4
      for (int k = 0; k < KTOT; k += 4) {
        const f32x4 z4 = *(const f32x4*)(zs + k);
        const f32x2 w0 = wp[(size_t)(k+0)*1024];
        const f32x2 w1 = wp[(size_t)(k+1)*1024];
        const f32x2 w2 = wp[(size_t)(k+2)*1024];
        const f32x2 w3 = wp[(size_t)(k+3)*1024];
        acc += w0*z4.x + w1*z4.y + w2*z4.z + w3*z4.w;
      }
    }
    __syncthreads();   // P2: everyone done reading zs

    // ---- P3: stage x_{t+1}; activations -> gact ----
    if (tid < 64 && t+1 < LL) *(f32x4*)(zs + 4*tid) = xr;
    {
      f32x2 s;
      if (g == 2) { s.x = tanhf(acc.x); s.y = tanhf(acc.y); }
      else        { s.x = 1.f/(1.f + expf(-acc.x)); s.y = 1.f/(1.f + expf(-acc.y)); }
      *(f32x2*)&gact[2*tid] = s;
    }
    __syncthreads();   // P4: gact + x ready

    // ---- P5: state update (threads 0..511 own hidden unit j) ----
    if (tid < HID) {
      const int j = tid;
      const float ig = gact[j],        fg = gact[HID + j];
      const float gg = gact[2*HID+j],  og = gact[3*HID+j];
      const float u  = u_s;
      const float cold = c_reg;
      const float cnew = fg*cold + ig*gg;
      const float ct   = u*cnew + (1.f-u)*cold;
      const float ht   = u*(og*tanhf(ct)) + (1.f-u)*zs[NB + j];
      c_reg = ct;
      zs[NB + j] = ht;
      if (t == LL-1) out[(size_t)b*HID + j] = ht;
      float p = ct * wuj;
#pragma unroll
      for (int off = 1; off < 64; off <<= 1) p += __shfl_xor(p, off);
      if ((tid & 63) == 0) part[tid >> 6] = p;
    }
    __syncthreads();   // P6: h written, partials ready

    // ---- P7: thread 0 finalizes u for step t+1 (read at next P5, after 2 syncs) ----
    if (tid == 0) {
      float s = 0.f;
#pragma unroll
      for (int i = 0; i < 8; ++i) s += part[i];
      const float du  = 1.f/(1.f + expf(-(s + buv)));
      const float utv = ut_s, up = u_s;
      const float utn = up*du + (1.f-up)*(utv + fminf(du, 1.f-utv));
      ut_s = utn;
      u_s  = rintf(utn);
    }
  }
}

extern "C" void kernel_launch(void* const* d_in, const int* in_sizes, int n_in,
                              void* d_out, int out_size, void* d_ws, size_t ws_size,
                              hipStream_t stream) {
  const float* x    = (const float*)d_in[0];
  const float* cw   = (const float*)d_in[1];
  const float* cb   = (const float*)d_in[2];
  const float* gma  = (const float*)d_in[3];
  const float* bta  = (const float*)d_in[4];
  const float* bmean= (const float*)d_in[5];
  const float* bvar = (const float*)d_in[6];
  const float* wih  = (const float*)d_in[7];
  const float* whh  = (const float*)d_in[8];
  const float* bih  = (const float*)d_in[9];
  const float* bhh  = (const float*)d_in[10];
  const float* wu   = (const float*)d_in[11];
  const float* bu   = (const float*)d_in[12];
  float* out = (float*)d_out;

  float* ws    = (float*)d_ws;
  float* seq   = ws;                                 // B*L*NB  = 8,355,840 f
  float* wT    = seq + (size_t)BB*LL*NB;             // 768*2048 = 1,572,864 f
  float* biasv = wT + (size_t)KTOT*ROWS;             // 2048 f   (~39.7 MB total)

  hipLaunchKernelGGL(prep_kernel, dim3((KTOT*ROWS)/256 + ROWS/256), dim3(256),
                     0, stream, wih, whh, bih, bhh, wT, biasv);
  hipLaunchKernelGGL(conv_kernel, dim3(16, 64), dim3(256), 0, stream,
                     x, cw, cb, gma, bta, bmean, bvar, seq);
  hipLaunchKernelGGL(rec_kernel, dim3(BB), dim3(1024), 0, stream,
                     seq, wT, biasv, wu, bu, out);
}

// Round 5
// 27746.069 us; speedup vs baseline: 1.5669x; 1.5669x over previous
//
#include <hip/hip_runtime.h>

typedef float f32x4 __attribute__((ext_vector_type(4)));

#define BB 64
#define TT 1024
#define DIN 128
#define NB 256
#define KW 5
#define HID 512
#define LL 510
#define LT 32
#define KTOT 768          // NB + HID
#define ROWS 2048         // 4*HID
#define KSPL 384          // k per thread-half
#define EPS 1e-5f

__device__ __forceinline__ float sigm(float x) { return 1.f/(1.f + expf(-x)); }

// ---------------- prep: wT[k][r] = W[r][k] (W = [W_ih | W_hh]), biasv = b_ih+b_hh ----
__global__ __launch_bounds__(256) void prep_kernel(
    const float* __restrict__ wih, const float* __restrict__ whh,
    const float* __restrict__ bih, const float* __restrict__ bhh,
    float* __restrict__ wT, float* __restrict__ biasv)
{
  const int blk = blockIdx.x, tid = threadIdx.x;
  if (blk < (KTOT*ROWS)/256) {
    const int e = blk*256 + tid;
    const int k = e >> 11, r = e & (ROWS-1);
    wT[e] = (k < NB) ? wih[(size_t)r*NB + k] : whh[(size_t)r*HID + (k-NB)];
  } else {
    const int r = (blk - (KTOT*ROWS)/256)*256 + tid;
    if (r < ROWS) biasv[r] = bih[r] + bhh[r];
  }
}

// ---------------- Conv1d + ReLU + BatchNorm (eval) -> seq[B][L][NB] ----------------
__global__ __launch_bounds__(256) void conv_kernel(
    const float* __restrict__ x, const float* __restrict__ cw,
    const float* __restrict__ cb, const float* __restrict__ gma,
    const float* __restrict__ bta, const float* __restrict__ bmean,
    const float* __restrict__ bvar, float* __restrict__ seq)
{
  __shared__ float xt[2*LT+3][DIN];
  const int b = blockIdx.y, lc = blockIdx.x, tid = threadIdx.x;
  const int l0 = lc*LT, t0 = l0*2;

  const float4* x4 = (const float4*)(x + ((size_t)b*TT + t0)*DIN);
  for (int i = tid; i < (2*LT+3)*(DIN/4); i += 256) {
    const int r = i >> 5, c = i & 31;
    float4 v = make_float4(0.f, 0.f, 0.f, 0.f);
    if (t0 + r < TT) v = x4[(size_t)r*(DIN/4) + c];
    ((float4*)xt[r])[c] = v;
  }
  __syncthreads();

  const int f = tid;
  float acc[LT];
#pragma unroll
  for (int l = 0; l < LT; ++l) acc[l] = 0.f;

  const float* wr = cw + (size_t)f*(DIN*KW);
  for (int d = 0; d < DIN; ++d) {
    float xr[2*LT+3];
#pragma unroll
    for (int r = 0; r < 2*LT+3; ++r) xr[r] = xt[r][d];
#pragma unroll
    for (int k = 0; k < KW; ++k) {
      const float w = wr[d*KW + k];
#pragma unroll
      for (int l = 0; l < LT; ++l) acc[l] += w * xr[2*l + k];
    }
  }

  const float bias  = cb[f];
  const float scale = gma[f] * rsqrtf(bvar[f] + EPS);
  const float shift = bta[f] - bmean[f]*scale;
#pragma unroll
  for (int l = 0; l < LT; ++l) {
    const int ll = l0 + l;
    if (ll < LL) {
      float y = acc[l] + bias;
      y = fmaxf(y, 0.f);
      seq[((size_t)b*LL + ll)*NB + f] = y*scale + shift;
    }
  }
}

// ---------------- SkipLSTM recurrence: one batch per block, deep-MLP GEMV ----------
// 64 blocks x 1024 threads. Thread (rg = tid&511, kh = tid>>9) accumulates rows
// 4rg..4rg+3 over k-half kh via 16B dwordx4 weight loads (unroll-8 -> ~8 loads in
// flight/wave). Partial halves combined in LDS; activation; state update; exact
// SkipRNN fast path: when u==0 the whole GEMV is skipped (c,h,du unchanged).
__global__ __launch_bounds__(1024) void rec_kernel(
    const float* __restrict__ seq, const float* __restrict__ wT,
    const float* __restrict__ biasv, const float* __restrict__ wu,
    const float* __restrict__ bu, float* __restrict__ out)
{
  __shared__ float zs[KTOT];          // [x(256) | h(512)]   3 KB
  __shared__ f32x4 part[512];         // kh=1 partial accs   8 KB
  __shared__ float gact[ROWS];        // activated gates     8 KB
  __shared__ f32x4 c_s[128];          // cell state          2 KB
  __shared__ float pw[2];             // wu-dot wave partials
  __shared__ int   u_lds;

  const int tid = threadIdx.x;
  const int rg  = tid & 511, kh = tid >> 9;
  const int b   = blockIdx.x;
  const float* seqb = seq + (size_t)b*LL*NB;

  // preloads
  f32x4 bias4;
  if (kh == 0) bias4 = ((const f32x4*)biasv)[rg];
  f32x4 wu4;
  if (tid < 128) wu4 = ((const f32x4*)wu)[tid];
  const float buv = bu[0];
  const int g = rg >> 7;              // gate of rows 4rg..4rg+3

  // thread-0 scalar state
  float ut_r = 1.f, dot_r = 0.f;
  int   u_r  = 1;

  // init: x_0, h_0 = 0, c = 0
  if (tid < 64)  *(f32x4*)(zs + 4*tid) = ((const f32x4*)seqb)[tid];
  if (tid < 128) *(f32x4*)(zs + NB + 4*tid) = f32x4{0.f,0.f,0.f,0.f};
  if (tid < 128) c_s[tid] = f32x4{0.f,0.f,0.f,0.f};
  if (tid == 0)  u_lds = 1;
  __syncthreads();

  for (int t = 0; t < LL; ++t) {
    const int u = __builtin_amdgcn_readfirstlane(u_lds);

    if (u) {
      // ---- GEMV: acc4 = sum over this thread's k-half ----
      f32x4 acc = {0.f, 0.f, 0.f, 0.f};
      {
        const int k0 = kh * KSPL;
        const f32x4* wp = (const f32x4*)(wT + (size_t)k0*ROWS) + rg;
#pragma unroll 2
        for (int k = 0; k < KSPL; k += 4) {
          const f32x4 z4 = *(const f32x4*)(zs + k0 + k);
          const f32x4 w0 = wp[0*512];
          const f32x4 w1 = wp[1*512];
          const f32x4 w2 = wp[2*512];
          const f32x4 w3 = wp[3*512];
          wp += 4*512;
          acc += w0*z4.x + w1*z4.y + w2*z4.z + w3*z4.w;
        }
      }
      if (kh == 1) part[rg] = acc;
      __syncthreads();                       // (1) partials ready

      // ---- combine + bias + activation (kh==0 threads) ----
      if (kh == 0) {
        f32x4 v = acc + part[rg] + bias4;
        f32x4 s;
        if (g == 2) {
          s.x = tanhf(v.x); s.y = tanhf(v.y); s.z = tanhf(v.z); s.w = tanhf(v.w);
        } else {
          s.x = sigm(v.x); s.y = sigm(v.y); s.z = sigm(v.z); s.w = sigm(v.w);
        }
        *(f32x4*)&gact[4*rg] = s;
      }
      __syncthreads();                       // (2) gact ready

      // ---- state update (u==1 exact: c=cnew, h=o*tanh(c)) ----
      if (tid < 128) {
        const int j = 4*tid;
        const f32x4 i4 = *(const f32x4*)&gact[j];
        const f32x4 f4 = *(const f32x4*)&gact[HID + j];
        const f32x4 g4 = *(const f32x4*)&gact[2*HID + j];
        const f32x4 o4 = *(const f32x4*)&gact[3*HID + j];
        const f32x4 c4 = c_s[tid];
        f32x4 ct = f4*c4 + i4*g4;
        f32x4 ht;
        ht.x = o4.x*tanhf(ct.x); ht.y = o4.y*tanhf(ct.y);
        ht.z = o4.z*tanhf(ct.z); ht.w = o4.w*tanhf(ct.w);
        c_s[tid] = ct;
        *(f32x4*)(zs + NB + j) = ht;
        float p = ct.x*wu4.x + ct.y*wu4.y + ct.z*wu4.z + ct.w*wu4.w;
#pragma unroll
        for (int off = 1; off < 64; off <<= 1) p += __shfl_xor(p, off);
        if ((tid & 63) == 0) pw[tid >> 6] = p;
      }
      __syncthreads();                       // (3) h + wu-partials ready

      if (tid == 0) {
        dot_r = pw[0] + pw[1];
        const float du = sigm(dot_r + buv);
        ut_r = du;                           // u was 1: ut_next = du exactly
        u_r  = (int)rintf(ut_r);
        u_lds = u_r;
      }
    } else {
      // ---- skip step: c,h,dot unchanged; only ut/u advance ----
      if (tid == 0) {
        const float du = sigm(dot_r + buv);
        ut_r = ut_r + fminf(du, 1.f - ut_r); // u was 0
        u_r  = (int)rintf(ut_r);
        u_lds = u_r;
      }
    }

    // ---- stage x_{t+1} (read by next update step's GEMV) ----
    if (tid < 64 && t+1 < LL)
      *(f32x4*)(zs + 4*tid) = *(const f32x4*)(seqb + (size_t)(t+1)*NB + 4*tid);
    __syncthreads();                         // (4/end) u_lds, x, h visible
  }

  // out = final h
  if (tid < 128)
    *(f32x4*)(out + (size_t)b*HID + 4*tid) = *(const f32x4*)(zs + NB + 4*tid);
}

extern "C" void kernel_launch(void* const* d_in, const int* in_sizes, int n_in,
                              void* d_out, int out_size, void* d_ws, size_t ws_size,
                              hipStream_t stream) {
  const float* x    = (const float*)d_in[0];
  const float* cw   = (const float*)d_in[1];
  const float* cb   = (const float*)d_in[2];
  const float* gma  = (const float*)d_in[3];
  const float* bta  = (const float*)d_in[4];
  const float* bmean= (const float*)d_in[5];
  const float* bvar = (const float*)d_in[6];
  const float* wih  = (const float*)d_in[7];
  const float* whh  = (const float*)d_in[8];
  const float* bih  = (const float*)d_in[9];
  const float* bhh  = (const float*)d_in[10];
  const float* wu   = (const float*)d_in[11];
  const float* bu   = (const float*)d_in[12];
  float* out = (float*)d_out;

  float* ws    = (float*)d_ws;
  float* seq   = ws;                                 // B*L*NB  = 8,355,840 f
  float* wT    = seq + (size_t)BB*LL*NB;             // 768*2048 = 1,572,864 f
  float* biasv = wT + (size_t)KTOT*ROWS;             // 2048 f

  hipLaunchKernelGGL(prep_kernel, dim3((KTOT*ROWS)/256 + ROWS/256), dim3(256),
                     0, stream, wih, whh, bih, bhh, wT, biasv);
  hipLaunchKernelGGL(conv_kernel, dim3(16, 64), dim3(256), 0, stream,
                     x, cw, cb, gma, bta, bmean, bvar, seq);
  hipLaunchKernelGGL(rec_kernel, dim3(BB), dim3(1024), 0, stream,
                     seq, wT, biasv, wu, bu, out);
}

// Round 6
// 11930.898 us; speedup vs baseline: 3.6440x; 2.3256x over previous
//
#include <hip/hip_runtime.h>

typedef float f32x4 __attribute__((ext_vector_type(4)));
typedef _Float16 f16x2 __attribute__((ext_vector_type(2)));
typedef _Float16 f16x4 __attribute__((ext_vector_type(4)));
typedef _Float16 f16x8 __attribute__((ext_vector_type(8)));

#define BB 64
#define TT 1024
#define DIN 128
#define NB 256
#define KW 5
#define HID 512
#define LL 510
#define LT 32
#define KTOT 768          // NB + HID
#define ROWS 2048         // 4*HID
#define KSPL 384          // k per thread-half
#define KP_PER 192        // k-pairs per thread-half
#define EPS 1e-5f

__device__ __forceinline__ float sigm(float x) { return 1.f/(1.f + expf(-x)); }

#if __has_builtin(__builtin_amdgcn_fdot2)
#define FDOT2(a, b, c) __builtin_amdgcn_fdot2((a), (b), (c), false)
#else
#define FDOT2(a, b, c) ((float)(a)[0]*(float)(b)[0] + (float)(a)[1]*(float)(b)[1] + (c))
#endif

// ---- prep: pack W = [W_ih | W_hh] into fp16, dot2-friendly layout ----
// half index e = ((kp*512)+rg)*8 + s, s in [0,8): row r = 4*rg + (s>>1),
// k = 2*kp + (s&1). One 16B load gives 4 rows x 1 k-pair.
__global__ __launch_bounds__(256) void prep_kernel(
    const float* __restrict__ wih, const float* __restrict__ whh,
    const float* __restrict__ bih, const float* __restrict__ bhh,
    _Float16* __restrict__ wTh, float* __restrict__ biasv)
{
  const int e = blockIdx.x*256 + threadIdx.x;
  if (e < KTOT*ROWS) {
    const int kp = e >> 12;
    const int rg = (e >> 3) & 511;
    const int s  = e & 7;
    const int r  = 4*rg + (s >> 1);
    const int k  = 2*kp + (s & 1);
    const float v = (k < NB) ? wih[(size_t)r*NB + k] : whh[(size_t)r*HID + (k-NB)];
    wTh[e] = (_Float16)v;
  } else if (e < KTOT*ROWS + ROWS) {
    const int r = e - KTOT*ROWS;
    biasv[r] = bih[r] + bhh[r];
  }
}

// ---------------- Conv1d + ReLU + BatchNorm (eval) -> seq[B][L][NB] ----------------
__global__ __launch_bounds__(256) void conv_kernel(
    const float* __restrict__ x, const float* __restrict__ cw,
    const float* __restrict__ cb, const float* __restrict__ gma,
    const float* __restrict__ bta, const float* __restrict__ bmean,
    const float* __restrict__ bvar, float* __restrict__ seq)
{
  __shared__ float xt[2*LT+3][DIN];
  const int b = blockIdx.y, lc = blockIdx.x, tid = threadIdx.x;
  const int l0 = lc*LT, t0 = l0*2;

  const float4* x4 = (const float4*)(x + ((size_t)b*TT + t0)*DIN);
  for (int i = tid; i < (2*LT+3)*(DIN/4); i += 256) {
    const int r = i >> 5, c = i & 31;
    float4 v = make_float4(0.f, 0.f, 0.f, 0.f);
    if (t0 + r < TT) v = x4[(size_t)r*(DIN/4) + c];
    ((float4*)xt[r])[c] = v;
  }
  __syncthreads();

  const int f = tid;
  float acc[LT];
#pragma unroll
  for (int l = 0; l < LT; ++l) acc[l] = 0.f;

  const float* wr = cw + (size_t)f*(DIN*KW);
  for (int d = 0; d < DIN; ++d) {
    float xr[2*LT+3];
#pragma unroll
    for (int r = 0; r < 2*LT+3; ++r) xr[r] = xt[r][d];
#pragma unroll
    for (int k = 0; k < KW; ++k) {
      const float w = wr[d*KW + k];
#pragma unroll
      for (int l = 0; l < LT; ++l) acc[l] += w * xr[2*l + k];
    }
  }

  const float bias  = cb[f];
  const float scale = gma[f] * rsqrtf(bvar[f] + EPS);
  const float shift = bta[f] - bmean[f]*scale;
#pragma unroll
  for (int l = 0; l < LT; ++l) {
    const int ll = l0 + l;
    if (ll < LL) {
      float y = acc[l] + bias;
      y = fmaxf(y, 0.f);
      seq[((size_t)b*LL + ll)*NB + f] = y*scale + shift;
    }
  }
}

// ---------------- SkipLSTM recurrence: one batch per block, fp16 dot2 GEMV --------
// 64 blocks x 1024 threads. Thread (rg = tid&511, kh = tid>>9) accumulates rows
// 4rg..4rg+3 over its k-half as 192 x {16B fp16 weight load + 1 LDS half2
// broadcast + 4 v_dot2_f32_f16}. 3 MB fp16 weight stream is per-XCD-L2-resident.
// z (x|h) kept fp16 in LDS; c, gates, du, ut, output h all f32.
__global__ __launch_bounds__(1024) void rec_kernel(
    const float* __restrict__ seq, const _Float16* __restrict__ wTh,
    const float* __restrict__ biasv, const float* __restrict__ wu,
    const float* __restrict__ bu, float* __restrict__ out)
{
  __shared__ alignas(16) _Float16 zs[KTOT];   // [x(256) | h(512)] fp16, 1.5 KB
  __shared__ f32x4 part[512];                 // kh=1 partial accs   8 KB
  __shared__ float gact[ROWS];                // activated gates     8 KB
  __shared__ f32x4 c_s[128];                  // cell state (f32)    2 KB
  __shared__ float pw[2];
  __shared__ int   u_lds;

  const int tid = threadIdx.x;
  const int rg  = tid & 511, kh = tid >> 9;
  const int b   = blockIdx.x;
  const float* seqb = seq + (size_t)b*LL*NB;

  f32x4 bias4 = {0.f,0.f,0.f,0.f};
  if (kh == 0) bias4 = ((const f32x4*)biasv)[rg];
  f32x4 wu4 = {0.f,0.f,0.f,0.f};
  if (tid < 128) wu4 = ((const f32x4*)wu)[tid];
  const float buv = bu[0];
  const int g = rg >> 7;                 // gate of rows 4rg..4rg+3
  f32x4 hreg = {0.f,0.f,0.f,0.f};        // f32 copy of this thread's 4 h values

  float ut_r = 1.f, dot_r = 0.f;         // thread-0 scalar state

  // init: x_0 (fp16), h_0 = 0, c = 0
  if (tid < 64) {
    const f32x4 x4 = ((const f32x4*)seqb)[tid];
    f16x4 xh; xh[0]=(_Float16)x4.x; xh[1]=(_Float16)x4.y;
    xh[2]=(_Float16)x4.z; xh[3]=(_Float16)x4.w;
    *(f16x4*)(zs + 4*tid) = xh;
  }
  if (tid < 128) {
    *(f16x4*)(zs + NB + 4*tid) = (f16x4){(_Float16)0,(_Float16)0,(_Float16)0,(_Float16)0};
    c_s[tid] = f32x4{0.f,0.f,0.f,0.f};
  }
  if (tid == 0) u_lds = 1;
  __syncthreads();

  for (int t = 0; t < LL; ++t) {
    const int u = u_lds;                 // LDS broadcast (valid via end-of-loop sync)

    if (u) {
      // ---- GEMV over this thread's k-half ----
      float a0 = 0.f, a1 = 0.f, a2 = 0.f, a3 = 0.f;
      {
        const f16x8* wp = (const f16x8*)wTh + (size_t)(kh*KP_PER)*512 + rg;
        const _Float16* zp = zs + kh*KSPL;
#pragma unroll 8
        for (int kp = 0; kp < KP_PER; ++kp) {
          const f16x8 w = wp[(size_t)kp*512];
          const f16x2 z = *(const f16x2*)(zp + 2*kp);
          a0 = FDOT2(__builtin_shufflevector(w, w, 0, 1), z, a0);
          a1 = FDOT2(__builtin_shufflevector(w, w, 2, 3), z, a1);
          a2 = FDOT2(__builtin_shufflevector(w, w, 4, 5), z, a2);
          a3 = FDOT2(__builtin_shufflevector(w, w, 6, 7), z, a3);
        }
      }
      if (kh == 1) part[rg] = f32x4{a0, a1, a2, a3};
      __syncthreads();                   // (1) partials ready

      // ---- combine + bias + activation ----
      if (kh == 0) {
        const f32x4 v = f32x4{a0, a1, a2, a3} + part[rg] + bias4;
        f32x4 s;
        if (g == 2) {
          s.x = tanhf(v.x); s.y = tanhf(v.y); s.z = tanhf(v.z); s.w = tanhf(v.w);
        } else {
          s.x = sigm(v.x); s.y = sigm(v.y); s.z = sigm(v.z); s.w = sigm(v.w);
        }
        *(f32x4*)&gact[4*rg] = s;
      }
      __syncthreads();                   // (2) gact ready

      // ---- state update (u==1 exact: c = cnew, h = o*tanh(c)) ----
      if (tid < 128) {
        const int j = 4*tid;
        const f32x4 i4 = *(const f32x4*)&gact[j];
        const f32x4 f4 = *(const f32x4*)&gact[HID + j];
        const f32x4 g4 = *(const f32x4*)&gact[2*HID + j];
        const f32x4 o4 = *(const f32x4*)&gact[3*HID + j];
        const f32x4 c4 = c_s[tid];
        const f32x4 ct = f4*c4 + i4*g4;
        f32x4 ht;
        ht.x = o4.x*tanhf(ct.x); ht.y = o4.y*tanhf(ct.y);
        ht.z = o4.z*tanhf(ct.z); ht.w = o4.w*tanhf(ct.w);
        c_s[tid] = ct;
        hreg = ht;
        f16x4 hh; hh[0]=(_Float16)ht.x; hh[1]=(_Float16)ht.y;
        hh[2]=(_Float16)ht.z; hh[3]=(_Float16)ht.w;
        *(f16x4*)(zs + NB + j) = hh;
        float p = ct.x*wu4.x + ct.y*wu4.y + ct.z*wu4.z + ct.w*wu4.w;
#pragma unroll
        for (int off = 1; off < 64; off <<= 1) p += __shfl_xor(p, off);
        if ((tid & 63) == 0) pw[tid >> 6] = p;
      }
      __syncthreads();                   // (3) h + wu-partials ready

      if (tid == 0) {
        dot_r = pw[0] + pw[1];
        const float du = sigm(dot_r + buv);
        ut_r = du;                       // u was 1: ut_next = du exactly
        u_lds = (int)rintf(ut_r);
      }
    } else {
      // ---- skip step: c,h,du unchanged; only ut/u advance (exact) ----
      if (tid == 0) {
        const float du = sigm(dot_r + buv);
        ut_r = ut_r + fminf(du, 1.f - ut_r);
        u_lds = (int)rintf(ut_r);
      }
    }

    // ---- stage x_{t+1} as fp16 ----
    if (tid < 64 && t+1 < LL) {
      const f32x4 x4 = *(const f32x4*)(seqb + (size_t)(t+1)*NB + 4*tid);
      f16x4 xh; xh[0]=(_Float16)x4.x; xh[1]=(_Float16)x4.y;
      xh[2]=(_Float16)x4.z; xh[3]=(_Float16)x4.w;
      *(f16x4*)(zs + 4*tid) = xh;
    }
    __syncthreads();                     // (end) u_lds, x, h visible
  }

  // out = final h (f32 registers, exact even if last steps were skips)
  if (tid < 128)
    *(f32x4*)(out + (size_t)b*HID + 4*tid) = hreg;
}

extern "C" void kernel_launch(void* const* d_in, const int* in_sizes, int n_in,
                              void* d_out, int out_size, void* d_ws, size_t ws_size,
                              hipStream_t stream) {
  const float* x    = (const float*)d_in[0];
  const float* cw   = (const float*)d_in[1];
  const float* cb   = (const float*)d_in[2];
  const float* gma  = (const float*)d_in[3];
  const float* bta  = (const float*)d_in[4];
  const float* bmean= (const float*)d_in[5];
  const float* bvar = (const float*)d_in[6];
  const float* wih  = (const float*)d_in[7];
  const float* whh  = (const float*)d_in[8];
  const float* bih  = (const float*)d_in[9];
  const float* bhh  = (const float*)d_in[10];
  const float* wu   = (const float*)d_in[11];
  const float* bu   = (const float*)d_in[12];
  float* out = (float*)d_out;

  float* ws       = (float*)d_ws;
  float* seq      = ws;                               // B*L*NB = 8,355,840 f
  _Float16* wTh   = (_Float16*)(seq + (size_t)BB*LL*NB);  // 1,572,864 halves = 3 MB
  float* biasv    = (float*)(wTh + (size_t)KTOT*ROWS);    // 2048 f

  hipLaunchKernelGGL(prep_kernel, dim3((KTOT*ROWS + ROWS + 255)/256), dim3(256),
                     0, stream, wih, whh, bih, bhh, wTh, biasv);
  hipLaunchKernelGGL(conv_kernel, dim3(16, 64), dim3(256), 0, stream,
                     x, cw, cb, gma, bta, bmean, bvar, seq);
  hipLaunchKernelGGL(rec_kernel, dim3(BB), dim3(1024), 0, stream,
                     seq, wTh, biasv, wu, bu, out);
}

// Round 7
// 9426.829 us; speedup vs baseline: 4.6120x; 1.2656x over previous
//
#include <hip/hip_runtime.h>

typedef float f32x4 __attribute__((ext_vector_type(4)));
typedef _Float16 f16x2 __attribute__((ext_vector_type(2)));
typedef _Float16 f16x4 __attribute__((ext_vector_type(4)));
typedef _Float16 f16x8 __attribute__((ext_vector_type(8)));

#define BB 64
#define TT 1024
#define DIN 128
#define NB 256
#define KW 5
#define HID 512
#define LL 510
#define LT 32
#define ROWS 2048         // 4*HID
#define CS 8              // xp chunk size (timesteps)
#define NHH (ROWS*HID)    // whhP halves
#define NIH (ROWS*NB)     // wihP halves
#define EPS 1e-5f

__device__ __forceinline__ float sigm(float x) { return 1.f/(1.f + expf(-x)); }

#if __has_builtin(__builtin_amdgcn_fdot2)
#define FDOT2(a, b, c) __builtin_amdgcn_fdot2((a), (b), (c), false)
#else
#define FDOT2(a, b, c) ((float)(a)[0]*(float)(b)[0] + (float)(a)[1]*(float)(b)[1] + (c))
#endif
#define SH(w, i) __builtin_shufflevector((w), (w), 2*(i), 2*(i)+1)

// ---- prep: pack W_hh and W_ih into fp16 dot2 layout ----
// half index e = ((kp*512)+rg)*8 + s : row r = 4*rg + (s>>1), k = 2*kp + (s&1).
// One 16B load = 4 rows x 1 k-pair.
__global__ __launch_bounds__(256) void prep_kernel(
    const float* __restrict__ wih, const float* __restrict__ whh,
    const float* __restrict__ bih, const float* __restrict__ bhh,
    _Float16* __restrict__ whhP, _Float16* __restrict__ wihP,
    float* __restrict__ biasv)
{
  const int e = blockIdx.x*256 + threadIdx.x;
  if (e < NHH) {
    const int kp = e >> 12, rg = (e >> 3) & 511, s = e & 7;
    const int r = 4*rg + (s >> 1), k = 2*kp + (s & 1);
    whhP[e] = (_Float16)whh[(size_t)r*HID + k];
  } else if (e < NHH + NIH) {
    const int e2 = e - NHH;
    const int kp = e2 >> 12, rg = (e2 >> 3) & 511, s = e2 & 7;
    const int r = 4*rg + (s >> 1), k = 2*kp + (s & 1);
    wihP[e2] = (_Float16)wih[(size_t)r*NB + k];
  } else if (e < NHH + NIH + ROWS) {
    const int r = e - NHH - NIH;
    biasv[r] = bih[r] + bhh[r];
  }
}

// ---------------- Conv1d + ReLU + BatchNorm (eval) -> seq[B][L][NB] ----------------
__global__ __launch_bounds__(256) void conv_kernel(
    const float* __restrict__ x, const float* __restrict__ cw,
    const float* __restrict__ cb, const float* __restrict__ gma,
    const float* __restrict__ bta, const float* __restrict__ bmean,
    const float* __restrict__ bvar, float* __restrict__ seq)
{
  __shared__ float xt[2*LT+3][DIN];
  const int b = blockIdx.y, lc = blockIdx.x, tid = threadIdx.x;
  const int l0 = lc*LT, t0 = l0*2;

  const float4* x4 = (const float4*)(x + ((size_t)b*TT + t0)*DIN);
  for (int i = tid; i < (2*LT+3)*(DIN/4); i += 256) {
    const int r = i >> 5, c = i & 31;
    float4 v = make_float4(0.f, 0.f, 0.f, 0.f);
    if (t0 + r < TT) v = x4[(size_t)r*(DIN/4) + c];
    ((float4*)xt[r])[c] = v;
  }
  __syncthreads();

  const int f = tid;
  float acc[LT];
#pragma unroll
  for (int l = 0; l < LT; ++l) acc[l] = 0.f;

  const float* wr = cw + (size_t)f*(DIN*KW);
  for (int d = 0; d < DIN; ++d) {
    float xr[2*LT+3];
#pragma unroll
    for (int r = 0; r < 2*LT+3; ++r) xr[r] = xt[r][d];
#pragma unroll
    for (int k = 0; k < KW; ++k) {
      const float w = wr[d*KW + k];
#pragma unroll
      for (int l = 0; l < LT; ++l) acc[l] += w * xr[2*l + k];
    }
  }

  const float bias  = cb[f];
  const float scale = gma[f] * rsqrtf(bvar[f] + EPS);
  const float shift = bta[f] - bmean[f]*scale;
#pragma unroll
  for (int l = 0; l < LT; ++l) {
    const int ll = l0 + l;
    if (ll < LL) {
      float y = acc[l] + bias;
      y = fmaxf(y, 0.f);
      seq[((size_t)b*LL + ll)*NB + f] = y*scale + shift;
    }
  }
}

// ---------------- SkipLSTM recurrence: 1 batch/block, hoisted x-projection --------
// 64 blocks x 1024 threads. Every CS steps: xp[CS][2048] = W_ih . x_{t0..t0+CS}
// computed in LDS (W_ih streamed once per chunk, reused across CS timesteps).
// Per step: GEMV streams only W_hh (2 MB fp16, per-XCD-L2-resident).
// Thread (rg = tid&511, kh = tid>>9): rows 4rg..4rg+3, k-half kh.
__global__ __launch_bounds__(1024) void rec_kernel(
    const float* __restrict__ seq, const _Float16* __restrict__ whhP,
    const _Float16* __restrict__ wihP, const float* __restrict__ biasv,
    const float* __restrict__ wu, const float* __restrict__ bu,
    float* __restrict__ out)
{
  __shared__ float xp[CS][ROWS];              // x-projection chunk   64 KB
  __shared__ f16x2 seqc[CS][NB/2];            // x chunk (fp16 pairs)  4 KB
  __shared__ alignas(16) _Float16 zs[HID];    // h (fp16)              1 KB
  __shared__ f32x4 part[512];                 // kh=1 partial accs     8 KB
  __shared__ float gact[ROWS];                // activated gates       8 KB
  __shared__ f32x4 c_s[128];                  // cell state (f32)      2 KB
  __shared__ float pw[2];
  __shared__ int   u_lds;

  const int tid = threadIdx.x;
  const int rg  = tid & 511, kh = tid >> 9;
  const int b   = blockIdx.x;
  const float* seqb = seq + (size_t)b*LL*NB;

  f32x4 bias4 = {0.f,0.f,0.f,0.f};
  if (kh == 0) bias4 = ((const f32x4*)biasv)[rg];
  f32x4 wu4 = {0.f,0.f,0.f,0.f};
  if (tid < 128) wu4 = ((const f32x4*)wu)[tid];
  const float buv = bu[0];
  const int g = rg >> 7;                 // gate of rows 4rg..4rg+3
  f32x4 hreg = {0.f,0.f,0.f,0.f};        // f32 copy of this thread's 4 h values

  float ut_r = 1.f, dot_r = 0.f;         // thread-0 scalar state

  // init: h_0 = 0, c = 0
  if (tid < 128) {
    *(f16x4*)(zs + 4*tid) = (f16x4){(_Float16)0,(_Float16)0,(_Float16)0,(_Float16)0};
    c_s[tid] = f32x4{0.f,0.f,0.f,0.f};
  }
  if (tid == 0) u_lds = 1;
  __syncthreads();

  for (int t0 = 0; t0 < LL; t0 += CS) {
    // ---- stage x chunk as fp16 pairs ----
    {
      const int tt = tid >> 7, kp = tid & 127;
      f16x2 v = {(_Float16)0, (_Float16)0};
      if (t0 + tt < LL) {
        const float* sp = seqb + (size_t)(t0+tt)*NB + 2*kp;
        v[0] = (_Float16)sp[0]; v[1] = (_Float16)sp[1];
      }
      seqc[tt][kp] = v;
    }
    __syncthreads();

    // ---- xp chunk GEMM: thread (rg, th) -> rows 4rg..4rg+3, timesteps 4th..4th+3 ----
    {
      const int th = kh;
      f32x4 acc[4] = {{0,0,0,0},{0,0,0,0},{0,0,0,0},{0,0,0,0}};
      const f16x8* wp = (const f16x8*)wihP + rg;
#pragma unroll 4
      for (int kp = 0; kp < 128; ++kp) {
        const f16x8 w = wp[(size_t)kp*512];
#pragma unroll
        for (int tt = 0; tt < 4; ++tt) {
          const f16x2 z = seqc[4*th + tt][kp];
          acc[tt].x = FDOT2(SH(w,0), z, acc[tt].x);
          acc[tt].y = FDOT2(SH(w,1), z, acc[tt].y);
          acc[tt].z = FDOT2(SH(w,2), z, acc[tt].z);
          acc[tt].w = FDOT2(SH(w,3), z, acc[tt].w);
        }
      }
#pragma unroll
      for (int tt = 0; tt < 4; ++tt)
        *(f32x4*)&xp[4*th + tt][4*rg] = acc[tt];
    }
    __syncthreads();

    const int tend = (t0 + CS < LL) ? t0 + CS : LL;
    for (int t = t0; t < tend; ++t) {
      const int u = u_lds;

      if (u) {
        // ---- W_hh GEMV over this thread's k-half (128 k-pairs) ----
        float a0 = 0.f, a1 = 0.f, a2 = 0.f, a3 = 0.f;
        {
          const f16x8* wp = (const f16x8*)whhP + (size_t)(kh*128)*512 + rg;
          const _Float16* zp = zs + kh*256;
#pragma unroll 8
          for (int kp = 0; kp < 128; ++kp) {
            const f16x8 w = wp[(size_t)kp*512];
            const f16x2 z = *(const f16x2*)(zp + 2*kp);
            a0 = FDOT2(SH(w,0), z, a0);
            a1 = FDOT2(SH(w,1), z, a1);
            a2 = FDOT2(SH(w,2), z, a2);
            a3 = FDOT2(SH(w,3), z, a3);
          }
        }
        if (kh == 1) part[rg] = f32x4{a0, a1, a2, a3};
        __syncthreads();                   // (1) partials ready

        // ---- combine + bias + xp + activation ----
        if (kh == 0) {
          const f32x4 v = f32x4{a0, a1, a2, a3} + part[rg] + bias4
                        + *(const f32x4*)&xp[t - t0][4*rg];
          f32x4 s;
          if (g == 2) {
            s.x = tanhf(v.x); s.y = tanhf(v.y); s.z = tanhf(v.z); s.w = tanhf(v.w);
          } else {
            s.x = sigm(v.x); s.y = sigm(v.y); s.z = sigm(v.z); s.w = sigm(v.w);
          }
          *(f32x4*)&gact[4*rg] = s;
        }
        __syncthreads();                   // (2) gact ready

        // ---- state update (u==1 exact: c = cnew, h = o*tanh(c)) ----
        if (tid < 128) {
          const int j = 4*tid;
          const f32x4 i4 = *(const f32x4*)&gact[j];
          const f32x4 f4 = *(const f32x4*)&gact[HID + j];
          const f32x4 g4 = *(const f32x4*)&gact[2*HID + j];
          const f32x4 o4 = *(const f32x4*)&gact[3*HID + j];
          const f32x4 c4 = c_s[tid];
          const f32x4 ct = f4*c4 + i4*g4;
          f32x4 ht;
          ht.x = o4.x*tanhf(ct.x); ht.y = o4.y*tanhf(ct.y);
          ht.z = o4.z*tanhf(ct.z); ht.w = o4.w*tanhf(ct.w);
          c_s[tid] = ct;
          hreg = ht;
          f16x4 hh; hh[0]=(_Float16)ht.x; hh[1]=(_Float16)ht.y;
          hh[2]=(_Float16)ht.z; hh[3]=(_Float16)ht.w;
          *(f16x4*)(zs + j) = hh;
          float p = ct.x*wu4.x + ct.y*wu4.y + ct.z*wu4.z + ct.w*wu4.w;
#pragma unroll
          for (int off = 1; off < 64; off <<= 1) p += __shfl_xor(p, off);
          if ((tid & 63) == 0) pw[tid >> 6] = p;
        }
        __syncthreads();                   // (3) h + wu-partials ready

        if (tid == 0) {
          dot_r = pw[0] + pw[1];
          const float du = sigm(dot_r + buv);
          ut_r = du;                       // u was 1: ut_next = du exactly
          u_lds = (int)rintf(ut_r);
        }
      } else {
        // ---- skip step: c,h,du unchanged; only ut/u advance (exact) ----
        if (tid == 0) {
          const float du = sigm(dot_r + buv);
          ut_r = ut_r + fminf(du, 1.f - ut_r);
          u_lds = (int)rintf(ut_r);
        }
      }
      __syncthreads();                     // (end) u_lds, h visible
    }
  }

  // out = final h (f32 registers, exact even if last steps were skips)
  if (tid < 128)
    *(f32x4*)(out + (size_t)b*HID + 4*tid) = hreg;
}

extern "C" void kernel_launch(void* const* d_in, const int* in_sizes, int n_in,
                              void* d_out, int out_size, void* d_ws, size_t ws_size,
                              hipStream_t stream) {
  const float* x    = (const float*)d_in[0];
  const float* cw   = (const float*)d_in[1];
  const float* cb   = (const float*)d_in[2];
  const float* gma  = (const float*)d_in[3];
  const float* bta  = (const float*)d_in[4];
  const float* bmean= (const float*)d_in[5];
  const float* bvar = (const float*)d_in[6];
  const float* wih  = (const float*)d_in[7];
  const float* whh  = (const float*)d_in[8];
  const float* bih  = (const float*)d_in[9];
  const float* bhh  = (const float*)d_in[10];
  const float* wu   = (const float*)d_in[11];
  const float* bu   = (const float*)d_in[12];
  float* out = (float*)d_out;

  float* ws     = (float*)d_ws;
  float* seq    = ws;                                   // B*L*NB = 8,355,840 f
  _Float16* whhP = (_Float16*)(seq + (size_t)BB*LL*NB); // 1,048,576 halves (2 MB)
  _Float16* wihP = whhP + (size_t)NHH;                  //   524,288 halves (1 MB)
  float* biasv   = (float*)(wihP + (size_t)NIH);        // 2048 f

  hipLaunchKernelGGL(prep_kernel, dim3((NHH + NIH + ROWS + 255)/256), dim3(256),
                     0, stream, wih, whh, bih, bhh, whhP, wihP, biasv);
  hipLaunchKernelGGL(conv_kernel, dim3(16, 64), dim3(256), 0, stream,
                     x, cw, cb, gma, bta, bmean, bvar, seq);
  hipLaunchKernelGGL(rec_kernel, dim3(BB), dim3(1024), 0, stream,
                     seq, whhP, wihP, biasv, wu, bu, out);
}

// Round 8
// 5900.764 us; speedup vs baseline: 7.3679x; 1.5976x over previous
//
#include <hip/hip_runtime.h>

typedef float f32x4 __attribute__((ext_vector_type(4)));
typedef _Float16 f16x2 __attribute__((ext_vector_type(2)));
typedef _Float16 f16x4 __attribute__((ext_vector_type(4)));
typedef _Float16 f16x8 __attribute__((ext_vector_type(8)));

#define BB 64
#define TT 1024
#define DIN 128
#define NB 256
#define KW 5
#define HID 512
#define LL 510
#define LT 32
#define ROWS 2048         // 4*HID
#define PR 1024           // rows per pair-block
#define RG 256            // row-groups (4 rows each) per block
#define CS 16             // xp chunk size (timesteps)
#define NHH2 (PR*HID)     // 524288 halves per p
#define NIH2 (PR*NB)      // 262144 halves per p
#define EPS 1e-5f

__device__ __forceinline__ float sigm(float x) { return 1.f/(1.f + expf(-x)); }

#if __has_builtin(__builtin_amdgcn_fdot2)
#define FDOT2(a, b, c) __builtin_amdgcn_fdot2((a), (b), (c), false)
#else
#define FDOT2(a, b, c) ((float)(a)[0]*(float)(b)[0] + (float)(a)[1]*(float)(b)[1] + (c))
#endif
#define SH(w, i) __builtin_shufflevector((w), (w), 2*(i), 2*(i)+1)

// ---------------- coherent helpers (sc0 sc1: write-through / bypass loads) --------
__device__ __forceinline__ void st16_sys(float* p, f32x4 v) {
  asm volatile("global_store_dwordx4 %0, %1, off sc0 sc1" :: "v"(p), "v"(v) : "memory");
}
__device__ __forceinline__ void st4_sys_u32(unsigned* p, unsigned v) {
  asm volatile("global_store_dword %0, %1, off sc0 sc1" :: "v"(p), "v"(v) : "memory");
}
__device__ __forceinline__ unsigned ld4_sys_u32(const unsigned* p) {
  unsigned v;
  asm volatile("global_load_dword %0, %1, off sc0 sc1\n\ts_waitcnt vmcnt(0)"
               : "=v"(v) : "v"(p) : "memory");
  return v;
}
__device__ __forceinline__ void ld16x2_sys(const float* a0, const float* a1,
                                           f32x4& r0, f32x4& r1) {
  asm volatile(
      "global_load_dwordx4 %0, %2, off sc0 sc1\n\t"
      "global_load_dwordx4 %1, %3, off sc0 sc1\n\t"
      "s_waitcnt vmcnt(0)"
      : "=&v"(r0), "=&v"(r1)
      : "v"(a0), "v"(a1)
      : "memory");
}

// ---- prep: pack W_hh / W_ih per pair-half into fp16 dot2 layout ----
// per half p: e = ((kp*RG)+rg)*8 + s : local row rl = 4rg+(s>>1), k = 2kp+(s&1),
// global row r = 1024p + rl. One 16B load = 4 rows x 1 k-pair.
__global__ __launch_bounds__(256) void prep_kernel(
    const float* __restrict__ wih, const float* __restrict__ whh,
    const float* __restrict__ bih, const float* __restrict__ bhh,
    _Float16* __restrict__ whhP2, _Float16* __restrict__ wihP2,
    float* __restrict__ biasv)
{
  const int e = blockIdx.x*256 + threadIdx.x;
  if (e < 2*NHH2) {
    const int p = e >> 19, e2 = e & (NHH2-1);
    const int kp = e2 >> 11, rg = (e2 >> 3) & 255, s = e2 & 7;
    const int r = (p << 10) + 4*rg + (s >> 1), k = 2*kp + (s & 1);
    whhP2[e] = (_Float16)whh[(size_t)r*HID + k];
  } else if (e < 2*NHH2 + 2*NIH2) {
    const int f = e - 2*NHH2;
    const int p = f >> 18, f2 = f & (NIH2-1);
    const int kp = f2 >> 11, rg = (f2 >> 3) & 255, s = f2 & 7;
    const int r = (p << 10) + 4*rg + (s >> 1), k = 2*kp + (s & 1);
    wihP2[f] = (_Float16)wih[(size_t)r*NB + k];
  } else if (e < 2*NHH2 + 2*NIH2 + ROWS) {
    const int r = e - 2*NHH2 - 2*NIH2;
    biasv[r] = bih[r] + bhh[r];
  }
}

// ---------------- Conv1d + ReLU + BatchNorm (eval) -> seq[B][L][NB] ----------------
__global__ __launch_bounds__(256) void conv_kernel(
    const float* __restrict__ x, const float* __restrict__ cw,
    const float* __restrict__ cb, const float* __restrict__ gma,
    const float* __restrict__ bta, const float* __restrict__ bmean,
    const float* __restrict__ bvar, float* __restrict__ seq)
{
  __shared__ float xt[2*LT+3][DIN];
  const int b = blockIdx.y, lc = blockIdx.x, tid = threadIdx.x;
  const int l0 = lc*LT, t0 = l0*2;

  const float4* x4 = (const float4*)(x + ((size_t)b*TT + t0)*DIN);
  for (int i = tid; i < (2*LT+3)*(DIN/4); i += 256) {
    const int r = i >> 5, c = i & 31;
    float4 v = make_float4(0.f, 0.f, 0.f, 0.f);
    if (t0 + r < TT) v = x4[(size_t)r*(DIN/4) + c];
    ((float4*)xt[r])[c] = v;
  }
  __syncthreads();

  const int f = tid;
  float acc[LT];
#pragma unroll
  for (int l = 0; l < LT; ++l) acc[l] = 0.f;

  const float* wr = cw + (size_t)f*(DIN*KW);
  for (int d = 0; d < DIN; ++d) {
    float xr[2*LT+3];
#pragma unroll
    for (int r = 0; r < 2*LT+3; ++r) xr[r] = xt[r][d];
#pragma unroll
    for (int k = 0; k < KW; ++k) {
      const float w = wr[d*KW + k];
#pragma unroll
      for (int l = 0; l < LT; ++l) acc[l] += w * xr[2*l + k];
    }
  }

  const float bias  = cb[f];
  const float scale = gma[f] * rsqrtf(bvar[f] + EPS);
  const float shift = bta[f] - bmean[f]*scale;
#pragma unroll
  for (int l = 0; l < LT; ++l) {
    const int ll = l0 + l;
    if (ll < LL) {
      float y = acc[l] + bias;
      y = fmaxf(y, 0.f);
      seq[((size_t)b*LL + ll)*NB + f] = y*scale + shift;
    }
  }
}

// ---------------- SkipLSTM recurrence: 2 blocks per batch (row-split) -------------
// 128 blocks x 1024 threads; block (b = blk>>1, p = blk&1) owns gate rows
// 1024p..1024p+1023 and streams only ITS 1 MB half of W_hh per step.
// Exchange per update step: write own activated gates (f32, 4 KB, sc0sc1,
// double-buffered) + flag=ustep; poll partner flag; read partner 4 KB.
// State update done redundantly in both blocks (bitwise identical -> identical
// u decisions, no further sync). xp chunk (CS=16) hoists W_ih.
__global__ __launch_bounds__(1024) void rec_kernel(
    const float* __restrict__ seq, const _Float16* __restrict__ whhP2,
    const _Float16* __restrict__ wihP2, const float* __restrict__ biasv,
    const float* __restrict__ wu, const float* __restrict__ bu,
    float* __restrict__ gx, unsigned* __restrict__ flags,
    float* __restrict__ out)
{
  __shared__ float xp[CS][PR];                // 64 KB
  __shared__ f16x2 seqc[CS][NB/2];            //  8 KB
  __shared__ alignas(16) _Float16 zs[HID];    //  1 KB (h, fp16)
  __shared__ f32x4 part[3][RG];               // 12 KB
  __shared__ float gown[PR];                  //  4 KB (own activated gates)
  __shared__ f32x4 c_s[128];                  //  2 KB (cell, f32)
  __shared__ float pw[2];
  __shared__ int   u_lds;

  const int tid = threadIdx.x;
  const int rg  = tid & 255, kh = tid >> 8;   // kh in [0,4)
  const int blk = blockIdx.x, b = blk >> 1, p = blk & 1;
  const float* seqb = seq + (size_t)b*LL*NB;
  const _Float16* whhB = whhP2 + (size_t)p*NHH2;
  const _Float16* wihB = wihP2 + (size_t)p*NIH2;
  float*       gx_own = gx + ((size_t)(b*2 + p))*2*PR;
  const float* gx_par = gx + ((size_t)(b*2 + (1-p)))*2*PR;
  unsigned*       flag_own = flags + (size_t)(b*2 + p)*32;
  const unsigned* flag_par = flags + (size_t)(b*2 + (1-p))*32;

  f32x4 bias4 = {0.f,0.f,0.f,0.f};
  if (kh == 0) bias4 = ((const f32x4*)biasv)[p*RG + rg];
  f32x4 wu4 = {0.f,0.f,0.f,0.f};
  if (tid < 128) wu4 = ((const f32x4*)wu)[tid];
  const float buv = bu[0];
  const int gate = 2*p + (rg >> 7);           // gate of own rows 4rg..4rg+3
  f32x4 hreg = {0.f,0.f,0.f,0.f};

  float ut_r = 1.f, dot_r = 0.f;
  int ustep = 0;

  if (tid < 128) {
    *(f16x4*)(zs + 4*tid) = (f16x4){(_Float16)0,(_Float16)0,(_Float16)0,(_Float16)0};
    c_s[tid] = f32x4{0.f,0.f,0.f,0.f};
  }
  if (tid == 0) u_lds = 1;
  __syncthreads();

  for (int t0 = 0; t0 < LL; t0 += CS) {
    // ---- stage x chunk as fp16 pairs (each thread 2 slots) ----
    {
      const int tt = tid >> 7, kp = tid & 127;
#pragma unroll
      for (int o = 0; o < CS; o += 8) {
        const int ttt = tt + o;
        f16x2 v = {(_Float16)0, (_Float16)0};
        if (t0 + ttt < LL) {
          const float* sp = seqb + (size_t)(t0+ttt)*NB + 2*kp;
          v[0] = (_Float16)sp[0]; v[1] = (_Float16)sp[1];
        }
        seqc[ttt][kp] = v;
      }
    }
    __syncthreads();

    // ---- xp chunk GEMM: thread (rg, kh) -> rows 4rg..4rg+3, timesteps 4kh..4kh+3 --
    {
      f32x4 acc[4] = {{0,0,0,0},{0,0,0,0},{0,0,0,0},{0,0,0,0}};
      const f16x8* wp = (const f16x8*)wihB + rg;
#pragma unroll 4
      for (int kp = 0; kp < 128; ++kp) {
        const f16x8 w = wp[(size_t)kp*RG];
#pragma unroll
        for (int tt = 0; tt < 4; ++tt) {
          const f16x2 z = seqc[4*kh + tt][kp];
          acc[tt].x = FDOT2(SH(w,0), z, acc[tt].x);
          acc[tt].y = FDOT2(SH(w,1), z, acc[tt].y);
          acc[tt].z = FDOT2(SH(w,2), z, acc[tt].z);
          acc[tt].w = FDOT2(SH(w,3), z, acc[tt].w);
        }
      }
#pragma unroll
      for (int tt = 0; tt < 4; ++tt)
        *(f32x4*)&xp[4*kh + tt][4*rg] = acc[tt];
    }
    __syncthreads();

    const int tend = (t0 + CS < LL) ? t0 + CS : LL;
    for (int t = t0; t < tend; ++t) {
      const int u = u_lds;

      if (u) {
        ustep++;
        // ---- W_hh half-GEMV: k-quarter kh (64 k-pairs) ----
        float a0 = 0.f, a1 = 0.f, a2 = 0.f, a3 = 0.f;
        {
          const f16x8* wp = (const f16x8*)whhB + ((size_t)(64*kh))*RG + rg;
          const _Float16* zp = zs + 128*kh;
#pragma unroll 8
          for (int kp = 0; kp < 64; ++kp) {
            const f16x8 w = wp[(size_t)kp*RG];
            const f16x2 z = *(const f16x2*)(zp + 2*kp);
            a0 = FDOT2(SH(w,0), z, a0);
            a1 = FDOT2(SH(w,1), z, a1);
            a2 = FDOT2(SH(w,2), z, a2);
            a3 = FDOT2(SH(w,3), z, a3);
          }
        }
        if (kh) part[kh-1][rg] = f32x4{a0, a1, a2, a3};
        __syncthreads();                        // (1) partials

        if (kh == 0) {
          f32x4 v = f32x4{a0, a1, a2, a3} + part[0][rg] + part[1][rg] + part[2][rg]
                  + bias4 + *(const f32x4*)&xp[t - t0][4*rg];
          f32x4 s;
          if (gate == 2) {
            s.x = tanhf(v.x); s.y = tanhf(v.y); s.z = tanhf(v.z); s.w = tanhf(v.w);
          } else {
            s.x = sigm(v.x); s.y = sigm(v.y); s.z = sigm(v.z); s.w = sigm(v.w);
          }
          *(f32x4*)&gown[4*rg] = s;
          st16_sys(gx_own + (size_t)(ustep & 1)*PR + 4*rg, s);
          asm volatile("s_waitcnt vmcnt(0)" ::: "memory");
        }
        __syncthreads();                        // (2) gx stores drained

        if (tid == 0) {
          st4_sys_u32(flag_own, (unsigned)ustep);
          unsigned f = ld4_sys_u32(flag_par);
          while (f < (unsigned)ustep) {
            __builtin_amdgcn_s_sleep(1);
            f = ld4_sys_u32(flag_par);
          }
        }
        __syncthreads();                        // (3) partner ready

        if (tid < 128) {
          const int j = 4*tid;
          const f32x4 ga = *(const f32x4*)&gown[j];
          const f32x4 gb = *(const f32x4*)&gown[512 + j];
          f32x4 gc, gd;
          ld16x2_sys(gx_par + (size_t)(ustep & 1)*PR + j,
                     gx_par + (size_t)(ustep & 1)*PR + 512 + j, gc, gd);
          f32x4 i4, f4, g4, o4;
          if (p == 0) { i4 = ga; f4 = gb; g4 = gc; o4 = gd; }
          else        { i4 = gc; f4 = gd; g4 = ga; o4 = gb; }
          const f32x4 c4 = c_s[tid];
          const f32x4 ct = f4*c4 + i4*g4;       // u==1 exact: c = cnew
          f32x4 ht;
          ht.x = o4.x*tanhf(ct.x); ht.y = o4.y*tanhf(ct.y);
          ht.z = o4.z*tanhf(ct.z); ht.w = o4.w*tanhf(ct.w);
          c_s[tid] = ct;
          hreg = ht;
          f16x4 hh; hh[0]=(_Float16)ht.x; hh[1]=(_Float16)ht.y;
          hh[2]=(_Float16)ht.z; hh[3]=(_Float16)ht.w;
          *(f16x4*)(zs + j) = hh;
          float pp = ct.x*wu4.x + ct.y*wu4.y + ct.z*wu4.z + ct.w*wu4.w;
#pragma unroll
          for (int off = 1; off < 64; off <<= 1) pp += __shfl_xor(pp, off);
          if ((tid & 63) == 0) pw[tid >> 6] = pp;
        }
        __syncthreads();                        // (4) h + wu-partials

        if (tid == 0) {
          dot_r = pw[0] + pw[1];
          const float du = sigm(dot_r + buv);
          ut_r = du;                            // u was 1: ut_next = du exactly
          u_lds = (int)rintf(ut_r);
        }
      } else {
        // ---- skip step: c,h,du unchanged; ut/u advance (identical in both) ----
        if (tid == 0) {
          const float du = sigm(dot_r + buv);
          ut_r = ut_r + fminf(du, 1.f - ut_r);
          u_lds = (int)rintf(ut_r);
        }
      }
      __syncthreads();                          // (5/end) u_lds, h visible
    }
  }

  if (tid < 128)
    *(f32x4*)(out + (size_t)b*HID + 4*tid) = hreg;
}

extern "C" void kernel_launch(void* const* d_in, const int* in_sizes, int n_in,
                              void* d_out, int out_size, void* d_ws, size_t ws_size,
                              hipStream_t stream) {
  const float* x    = (const float*)d_in[0];
  const float* cw   = (const float*)d_in[1];
  const float* cb   = (const float*)d_in[2];
  const float* gma  = (const float*)d_in[3];
  const float* bta  = (const float*)d_in[4];
  const float* bmean= (const float*)d_in[5];
  const float* bvar = (const float*)d_in[6];
  const float* wih  = (const float*)d_in[7];
  const float* whh  = (const float*)d_in[8];
  const float* bih  = (const float*)d_in[9];
  const float* bhh  = (const float*)d_in[10];
  const float* wu   = (const float*)d_in[11];
  const float* bu   = (const float*)d_in[12];
  float* out = (float*)d_out;

  float* ws       = (float*)d_ws;
  float* seq      = ws;                                    // 8,355,840 f
  _Float16* whhP2 = (_Float16*)(seq + (size_t)BB*LL*NB);   // 2*524288 h (2 MB)
  _Float16* wihP2 = whhP2 + (size_t)2*NHH2;                // 2*262144 h (1 MB)
  float* biasv    = (float*)(wihP2 + (size_t)2*NIH2);      // 2048 f
  float* gx       = biasv + ROWS;                          // 64*2*2*1024 f (1 MB)
  unsigned* flags = (unsigned*)(gx + (size_t)BB*2*2*PR);   // 64*2*32 u32 (16 KB)

  hipMemsetAsync(flags, 0, (size_t)BB*2*32*sizeof(unsigned), stream);

  hipLaunchKernelGGL(prep_kernel,
                     dim3((2*NHH2 + 2*NIH2 + ROWS + 255)/256), dim3(256),
                     0, stream, wih, whh, bih, bhh, whhP2, wihP2, biasv);
  hipLaunchKernelGGL(conv_kernel, dim3(16, 64), dim3(256), 0, stream,
                     x, cw, cb, gma, bta, bmean, bvar, seq);
  hipLaunchKernelGGL(rec_kernel, dim3(2*BB), dim3(1024), 0, stream,
                     seq, whhP2, wihP2, biasv, wu, bu, gx, flags, out);
}

// Round 9
// 4166.474 us; speedup vs baseline: 10.4348x; 1.4162x over previous
//
#include <hip/hip_runtime.h>

typedef float f32x4 __attribute__((ext_vector_type(4)));
typedef _Float16 f16x2 __attribute__((ext_vector_type(2)));
typedef _Float16 f16x4 __attribute__((ext_vector_type(4)));
typedef _Float16 f16x8 __attribute__((ext_vector_type(8)));

#define BB 64
#define TT 1024
#define DIN 128
#define NB 256
#define KW 5
#define HID 512
#define LL 510
#define LT 32
#define ROWS 2048         // 4*HID
#define BPB 4             // blocks per batch
#define PRQ 512           // rows per block (one gate)
#define RGQ 128           // row-groups (4 rows) per block
#define CS 16             // xp chunk size (timesteps)
#define NHH4 (PRQ*HID)    // 262144 halves per quarter (2^18)
#define NIH4 (PRQ*NB)     // 131072 halves per quarter (2^17)
#define EPS 1e-5f

__device__ __forceinline__ float sigm(float x) { return 1.f/(1.f + expf(-x)); }

#if __has_builtin(__builtin_amdgcn_fdot2)
#define FDOT2(a, b, c) __builtin_amdgcn_fdot2((a), (b), (c), false)
#else
#define FDOT2(a, b, c) ((float)(a)[0]*(float)(b)[0] + (float)(a)[1]*(float)(b)[1] + (c))
#endif
#define SH(w, i) __builtin_shufflevector((w), (w), 2*(i), 2*(i)+1)

// ---------------- coherent helpers (sc0 sc1: write-through / bypass loads) --------
__device__ __forceinline__ void st16_sys(float* p, f32x4 v) {
  asm volatile("global_store_dwordx4 %0, %1, off sc0 sc1" :: "v"(p), "v"(v) : "memory");
}
__device__ __forceinline__ void st4_sys_u32(unsigned* p, unsigned v) {
  asm volatile("global_store_dword %0, %1, off sc0 sc1" :: "v"(p), "v"(v) : "memory");
}
__device__ __forceinline__ unsigned ld4_sys_u32(const unsigned* p) {
  unsigned v;
  asm volatile("global_load_dword %0, %1, off sc0 sc1\n\ts_waitcnt vmcnt(0)"
               : "=v"(v) : "v"(p) : "memory");
  return v;
}
__device__ __forceinline__ void ld16x3_sys(const float* a0, const float* a1,
                                           const float* a2,
                                           f32x4& r0, f32x4& r1, f32x4& r2) {
  asm volatile(
      "global_load_dwordx4 %0, %3, off sc0 sc1\n\t"
      "global_load_dwordx4 %1, %4, off sc0 sc1\n\t"
      "global_load_dwordx4 %2, %5, off sc0 sc1\n\t"
      "s_waitcnt vmcnt(0)"
      : "=&v"(r0), "=&v"(r1), "=&v"(r2)
      : "v"(a0), "v"(a1), "v"(a2)
      : "memory");
}

// ---- prep: pack W_hh / W_ih per quarter into fp16 dot2 layout ----
// per quarter p: e = ((kp*RGQ)+rg)*8 + s : local row rl = 4rg+(s>>1),
// k = 2kp+(s&1), global row r = 512p + rl. One 16B load = 4 rows x 1 k-pair.
__global__ __launch_bounds__(256) void prep_kernel(
    const float* __restrict__ wih, const float* __restrict__ whh,
    const float* __restrict__ bih, const float* __restrict__ bhh,
    _Float16* __restrict__ whhP4, _Float16* __restrict__ wihP4,
    float* __restrict__ biasv)
{
  const int e = blockIdx.x*256 + threadIdx.x;
  if (e < 4*NHH4) {
    const int p = e >> 18, e2 = e & (NHH4-1);
    const int kp = e2 >> 10, rg = (e2 >> 3) & 127, s = e2 & 7;
    const int r = (p << 9) + 4*rg + (s >> 1), k = 2*kp + (s & 1);
    whhP4[e] = (_Float16)whh[(size_t)r*HID + k];
  } else if (e < 4*NHH4 + 4*NIH4) {
    const int f = e - 4*NHH4;
    const int p = f >> 17, f2 = f & (NIH4-1);
    const int kp = f2 >> 10, rg = (f2 >> 3) & 127, s = f2 & 7;
    const int r = (p << 9) + 4*rg + (s >> 1), k = 2*kp + (s & 1);
    wihP4[f] = (_Float16)wih[(size_t)r*NB + k];
  } else if (e < 4*NHH4 + 4*NIH4 + ROWS) {
    const int r = e - 4*NHH4 - 4*NIH4;
    biasv[r] = bih[r] + bhh[r];
  }
}

// ---------------- Conv1d + ReLU + BatchNorm (eval) -> seq[B][L][NB] ----------------
__global__ __launch_bounds__(256) void conv_kernel(
    const float* __restrict__ x, const float* __restrict__ cw,
    const float* __restrict__ cb, const float* __restrict__ gma,
    const float* __restrict__ bta, const float* __restrict__ bmean,
    const float* __restrict__ bvar, float* __restrict__ seq)
{
  __shared__ float xt[2*LT+3][DIN];
  const int b = blockIdx.y, lc = blockIdx.x, tid = threadIdx.x;
  const int l0 = lc*LT, t0 = l0*2;

  const float4* x4 = (const float4*)(x + ((size_t)b*TT + t0)*DIN);
  for (int i = tid; i < (2*LT+3)*(DIN/4); i += 256) {
    const int r = i >> 5, c = i & 31;
    float4 v = make_float4(0.f, 0.f, 0.f, 0.f);
    if (t0 + r < TT) v = x4[(size_t)r*(DIN/4) + c];
    ((float4*)xt[r])[c] = v;
  }
  __syncthreads();

  const int f = tid;
  float acc[LT];
#pragma unroll
  for (int l = 0; l < LT; ++l) acc[l] = 0.f;

  const float* wr = cw + (size_t)f*(DIN*KW);
  for (int d = 0; d < DIN; ++d) {
    float xr[2*LT+3];
#pragma unroll
    for (int r = 0; r < 2*LT+3; ++r) xr[r] = xt[r][d];
#pragma unroll
    for (int k = 0; k < KW; ++k) {
      const float w = wr[d*KW + k];
#pragma unroll
      for (int l = 0; l < LT; ++l) acc[l] += w * xr[2*l + k];
    }
  }

  const float bias  = cb[f];
  const float scale = gma[f] * rsqrtf(bvar[f] + EPS);
  const float shift = bta[f] - bmean[f]*scale;
#pragma unroll
  for (int l = 0; l < LT; ++l) {
    const int ll = l0 + l;
    if (ll < LL) {
      float y = acc[l] + bias;
      y = fmaxf(y, 0.f);
      seq[((size_t)b*LL + ll)*NB + f] = y*scale + shift;
    }
  }
}

// ---------------- SkipLSTM recurrence: 4 blocks per batch (one gate each) ---------
// 256 blocks x 1024 threads; block (b = blk>>2, p = blk&3) owns gate p
// (rows 512p..512p+511) and streams only ITS 0.5 MB quarter of W_hh per step.
// Exchange per update step: store own activated gate (f32, 2 KB, sc0sc1,
// parity double-buffer) + flag; lanes 0-2 poll the 3 partner flags in parallel;
// read partners' 2 KB each. State update redundant in all 4 blocks (bitwise
// identical -> identical u decisions). xp chunk (CS=16) hoists W_ih quarter.
__global__ __launch_bounds__(1024) void rec_kernel(
    const float* __restrict__ seq, const _Float16* __restrict__ whhP4,
    const _Float16* __restrict__ wihP4, const float* __restrict__ biasv,
    const float* __restrict__ wu, const float* __restrict__ bu,
    float* __restrict__ gx, unsigned* __restrict__ flags,
    float* __restrict__ out)
{
  __shared__ float xp[CS][PRQ];               // 32 KB
  __shared__ f16x2 seqc[CS][NB/2];            //  8 KB
  __shared__ alignas(16) _Float16 zs[HID];    //  1 KB (h, fp16)
  __shared__ f32x4 part[7][RGQ];              // 14 KB
  __shared__ float gown[PRQ];                 //  2 KB (own activated gate)
  __shared__ f32x4 c_s[128];                  //  2 KB (cell, f32)
  __shared__ float pw[2];
  __shared__ int   u_lds;

  const int tid = threadIdx.x;
  const int rg  = tid & 127, kh = tid >> 7;   // kh in [0,8)
  const int blk = blockIdx.x, b = blk >> 2, p = blk & 3;
  const float* seqb = seq + (size_t)b*LL*NB;
  const _Float16* whhB = whhP4 + (size_t)p*NHH4;
  const _Float16* wihB = wihP4 + (size_t)p*NIH4;
  float* gx_b = gx + (size_t)b*BPB*2*PRQ;     // [4 blocks][2 buf][512]
  unsigned* flags_b = flags + (size_t)b*BPB*32;

  f32x4 bias4 = {0.f,0.f,0.f,0.f};
  if (kh == 0) bias4 = ((const f32x4*)biasv)[p*RGQ + rg];
  f32x4 wu4 = {0.f,0.f,0.f,0.f};
  if (tid < 128) wu4 = ((const f32x4*)wu)[tid];
  const float buv = bu[0];
  f32x4 hreg = {0.f,0.f,0.f,0.f};

  float ut_r = 1.f, dot_r = 0.f;
  int ustep = 0;

  if (tid < 128) {
    *(f16x4*)(zs + 4*tid) = (f16x4){(_Float16)0,(_Float16)0,(_Float16)0,(_Float16)0};
    c_s[tid] = f32x4{0.f,0.f,0.f,0.f};
  }
  if (tid == 0) u_lds = 1;
  __syncthreads();

  for (int t0 = 0; t0 < LL; t0 += CS) {
    // ---- stage x chunk as fp16 pairs (each thread 2 slots) ----
    {
      const int tt = tid >> 7, kp = tid & 127;
#pragma unroll
      for (int o = 0; o < CS; o += 8) {
        const int ttt = tt + o;
        f16x2 v = {(_Float16)0, (_Float16)0};
        if (t0 + ttt < LL) {
          const float* sp = seqb + (size_t)(t0+ttt)*NB + 2*kp;
          v[0] = (_Float16)sp[0]; v[1] = (_Float16)sp[1];
        }
        seqc[ttt][kp] = v;
      }
    }
    __syncthreads();

    // ---- xp chunk GEMM: thread (rg, kh) -> rows 4rg..4rg+3, timesteps 2kh,2kh+1 --
    {
      f32x4 acc[2] = {{0,0,0,0},{0,0,0,0}};
      const f16x8* wp = (const f16x8*)wihB + rg;
#pragma unroll 4
      for (int kp = 0; kp < 128; ++kp) {
        const f16x8 w = wp[(size_t)kp*RGQ];
#pragma unroll
        for (int tt = 0; tt < 2; ++tt) {
          const f16x2 z = seqc[2*kh + tt][kp];
          acc[tt].x = FDOT2(SH(w,0), z, acc[tt].x);
          acc[tt].y = FDOT2(SH(w,1), z, acc[tt].y);
          acc[tt].z = FDOT2(SH(w,2), z, acc[tt].z);
          acc[tt].w = FDOT2(SH(w,3), z, acc[tt].w);
        }
      }
#pragma unroll
      for (int tt = 0; tt < 2; ++tt)
        *(f32x4*)&xp[2*kh + tt][4*rg] = acc[tt];
    }
    __syncthreads();

    const int tend = (t0 + CS < LL) ? t0 + CS : LL;
    for (int t = t0; t < tend; ++t) {
      const int u = u_lds;

      if (u) {
        ustep++;
        const int buf = ustep & 1;
        // ---- W_hh quarter-GEMV: k-slice kh (32 k-pairs) ----
        float a0 = 0.f, a1 = 0.f, a2 = 0.f, a3 = 0.f;
        {
          const f16x8* wp = (const f16x8*)whhB + ((size_t)(32*kh))*RGQ + rg;
          const _Float16* zp = zs + 64*kh;
#pragma unroll 8
          for (int kp = 0; kp < 32; ++kp) {
            const f16x8 w = wp[(size_t)kp*RGQ];
            const f16x2 z = *(const f16x2*)(zp + 2*kp);
            a0 = FDOT2(SH(w,0), z, a0);
            a1 = FDOT2(SH(w,1), z, a1);
            a2 = FDOT2(SH(w,2), z, a2);
            a3 = FDOT2(SH(w,3), z, a3);
          }
        }
        if (kh) part[kh-1][rg] = f32x4{a0, a1, a2, a3};
        __syncthreads();                        // (1) partials

        if (kh == 0) {
          f32x4 v = f32x4{a0, a1, a2, a3} + bias4 + *(const f32x4*)&xp[t - t0][4*rg];
#pragma unroll
          for (int q = 0; q < 7; ++q) v += part[q][rg];
          f32x4 s;
          if (p == 2) {
            s.x = tanhf(v.x); s.y = tanhf(v.y); s.z = tanhf(v.z); s.w = tanhf(v.w);
          } else {
            s.x = sigm(v.x); s.y = sigm(v.y); s.z = sigm(v.z); s.w = sigm(v.w);
          }
          *(f32x4*)&gown[4*rg] = s;
          st16_sys(gx_b + ((size_t)p*2 + buf)*PRQ + 4*rg, s);
          asm volatile("s_waitcnt vmcnt(0)" ::: "memory");
        }
        __syncthreads();                        // (2) gx stores drained

        if (tid == 0) st4_sys_u32(flags_b + p*32, (unsigned)ustep);
        if (tid < 3) {
          const int q = (p + 1 + tid) & 3;
          const unsigned* fp = flags_b + q*32;
          unsigned f = ld4_sys_u32(fp);
          while (f < (unsigned)ustep) {
            __builtin_amdgcn_s_sleep(1);
            f = ld4_sys_u32(fp);
          }
        }
        __syncthreads();                        // (3) partners ready

        if (tid < 128) {
          const int j = 4*tid;
          const int q1 = (p+1)&3, q2 = (p+2)&3, q3 = (p+3)&3;
          f32x4 gv[4];
          gv[p] = *(const f32x4*)&gown[j];
          ld16x3_sys(gx_b + ((size_t)q1*2 + buf)*PRQ + j,
                     gx_b + ((size_t)q2*2 + buf)*PRQ + j,
                     gx_b + ((size_t)q3*2 + buf)*PRQ + j,
                     gv[q1], gv[q2], gv[q3]);
          const f32x4 i4 = gv[0], f4 = gv[1], g4 = gv[2], o4 = gv[3];
          const f32x4 c4 = c_s[tid];
          const f32x4 ct = f4*c4 + i4*g4;       // u==1 exact: c = cnew
          f32x4 ht;
          ht.x = o4.x*tanhf(ct.x); ht.y = o4.y*tanhf(ct.y);
          ht.z = o4.z*tanhf(ct.z); ht.w = o4.w*tanhf(ct.w);
          c_s[tid] = ct;
          hreg = ht;
          f16x4 hh; hh[0]=(_Float16)ht.x; hh[1]=(_Float16)ht.y;
          hh[2]=(_Float16)ht.z; hh[3]=(_Float16)ht.w;
          *(f16x4*)(zs + j) = hh;
          float pp = ct.x*wu4.x + ct.y*wu4.y + ct.z*wu4.z + ct.w*wu4.w;
#pragma unroll
          for (int off = 1; off < 64; off <<= 1) pp += __shfl_xor(pp, off);
          if ((tid & 63) == 0) pw[tid >> 6] = pp;
        }
        __syncthreads();                        // (4) h + wu-partials

        if (tid == 0) {
          dot_r = pw[0] + pw[1];
          const float du = sigm(dot_r + buv);
          ut_r = du;                            // u was 1: ut_next = du exactly
          u_lds = (int)rintf(ut_r);
        }
      } else {
        // ---- skip step: c,h,du unchanged; ut/u advance (identical in all 4) ----
        if (tid == 0) {
          const float du = sigm(dot_r + buv);
          ut_r = ut_r + fminf(du, 1.f - ut_r);
          u_lds = (int)rintf(ut_r);
        }
      }
      __syncthreads();                          // (5/end) u_lds, h visible
    }
  }

  if (p == 0 && tid < 128)
    *(f32x4*)(out + (size_t)b*HID + 4*tid) = hreg;
}

extern "C" void kernel_launch(void* const* d_in, const int* in_sizes, int n_in,
                              void* d_out, int out_size, void* d_ws, size_t ws_size,
                              hipStream_t stream) {
  const float* x    = (const float*)d_in[0];
  const float* cw   = (const float*)d_in[1];
  const float* cb   = (const float*)d_in[2];
  const float* gma  = (const float*)d_in[3];
  const float* bta  = (const float*)d_in[4];
  const float* bmean= (const float*)d_in[5];
  const float* bvar = (const float*)d_in[6];
  const float* wih  = (const float*)d_in[7];
  const float* whh  = (const float*)d_in[8];
  const float* bih  = (const float*)d_in[9];
  const float* bhh  = (const float*)d_in[10];
  const float* wu   = (const float*)d_in[11];
  const float* bu   = (const float*)d_in[12];
  float* out = (float*)d_out;

  float* ws       = (float*)d_ws;
  float* seq      = ws;                                    // 8,355,840 f
  _Float16* whhP4 = (_Float16*)(seq + (size_t)BB*LL*NB);   // 4*262144 h (2 MB)
  _Float16* wihP4 = whhP4 + (size_t)4*NHH4;                // 4*131072 h (1 MB)
  float* biasv    = (float*)(wihP4 + (size_t)4*NIH4);      // 2048 f
  float* gx       = biasv + ROWS;                          // 64*4*2*512 f (1 MB)
  unsigned* flags = (unsigned*)(gx + (size_t)BB*BPB*2*PRQ);// 64*4*32 u32 (32 KB)

  hipMemsetAsync(flags, 0, (size_t)BB*BPB*32*sizeof(unsigned), stream);

  hipLaunchKernelGGL(prep_kernel,
                     dim3((4*NHH4 + 4*NIH4 + ROWS + 255)/256), dim3(256),
                     0, stream, wih, whh, bih, bhh, whhP4, wihP4, biasv);
  hipLaunchKernelGGL(conv_kernel, dim3(16, 64), dim3(256), 0, stream,
                     x, cw, cb, gma, bta, bmean, bvar, seq);
  hipLaunchKernelGGL(rec_kernel, dim3(BPB*BB), dim3(1024), 0, stream,
                     seq, whhP4, wihP4, biasv, wu, bu, gx, flags, out);
}